// Round 2
// baseline (658.526 us; speedup 1.0000x reference)
//
#include <hip/hip_runtime.h>

#define N_NODES 100000
#define N_EDGES 1600000
#define N_GRAPHS 512
#define HID 64
#define NUM_CLASSES 100
#define ID_OFFSET 1500
#define BN_EPS 1e-5f
#define CAP 64
#define NBKT 256
#define BSHIFT 9
#define NUSED ((N_NODES + 511) >> 9)   // 196 buckets of 512 nodes
#define BCAP 10240                      // per-bucket record capacity
#define CBLK 98
#define CHUNK 16384
#define WPBLK 5                         // wprep blocks inside prep_kernel
#define EMBBLK ((N_NODES * 32 + 1023) / 1024)   // 3125
#define DUMMY_ROW 100000                // zeroed row in x-buffer slack, pad target

typedef __attribute__((ext_vector_type(8))) short short8;
typedef __attribute__((ext_vector_type(4))) float floatx4;

__device__ __forceinline__ float b2f(unsigned short u) {
    return __builtin_bit_cast(float, ((unsigned)u) << 16);
}
__device__ __forceinline__ unsigned short f2b(float f) {   // RNE
    unsigned x = __builtin_bit_cast(unsigned, f);
    x += 0x7FFFu + ((x >> 16) & 1u);
    return (unsigned short)(x >> 16);
}

// swizzled granule layout: 16-row tiles, 8 granules(16B)/row, granule slot = (row&15)^q
#define XSH(row, qq) ((((((row) >> 4) << 7) + ((qq) << 4) + (((row) & 15) ^ (qq))) * 8))

// ---------------- fused prep: direct-binning build + wprep + embed in one launch ----------------

__global__ __launch_bounds__(1024) void prep_kernel(const int* __restrict__ src,
                                                    const int* __restrict__ dst,
                                                    int* __restrict__ cursor,
                                                    int* __restrict__ rec,
                                                    const float* __restrict__ Ws,
                                                    unsigned short* __restrict__ whi,
                                                    unsigned short* __restrict__ wlo,
                                                    const int* __restrict__ node_ids,
                                                    const int* __restrict__ gid,
                                                    const float* __restrict__ emb,
                                                    unsigned short* __restrict__ h,
                                                    int* __restrict__ gs,
                                                    int* __restrict__ ge) {
    __shared__ int hist[NBKT];
    __shared__ int base_s[NBKT];
    int t = threadIdx.x;
    int blk = blockIdx.x;

    if (blk < CBLK) {
        // ---- edge binning (one pass) ----
        if (t < NBKT) hist[t] = 0;
        __syncthreads();
        int cb = blk * CHUNK;
        int d_[16], s_[16];
#pragma unroll
        for (int k = 0; k < 16; ++k) {
            int i = cb + k * 1024 + t;
            d_[k] = (i < N_EDGES) ? dst[i] : -1;
            s_[k] = (i < N_EDGES) ? src[i] : 0;
            if (d_[k] >= 0) atomicAdd(&hist[((unsigned)d_[k] >> BSHIFT) & (NBKT - 1)], 1);
        }
        __syncthreads();
        if (t < NBKT) base_s[t] = (hist[t] > 0) ? atomicAdd(&cursor[t], hist[t]) : 0;
        __syncthreads();
        if (t < NBKT) hist[t] = 0;
        __syncthreads();
#pragma unroll
        for (int k = 0; k < 16; ++k) {
            if (d_[k] >= 0) {
                unsigned d = (unsigned)d_[k];
                int b = (d >> BSHIFT) & (NBKT - 1);
                int p = atomicAdd(&hist[b], 1);
                int g = base_s[b] + p;
                if ((unsigned)g < BCAP)
                    rec[b * BCAP + g] = ((int)(d & 511) << 17) | (s_[k] & 0x1FFFF);
            }
        }
    } else if (blk < CBLK + WPBLK) {
        // ---- W pre-convert + pre-swizzle, hi/lo split ----
        int G = (blk - CBLK) * 1024 + t;
        if (G < 3 * 1536) {
            int l = G / 1536, Gp = G % 1536;
            int mm = Gp >> 9, rem = Gp & 511;
            int kq = rem >> 6, n = rem & 63;
            const float* Wp = Ws + l * 12288 + mm * 4096 + (kq * 8) * 64 + n;
            unsigned short uh[8], ul[8];
#pragma unroll
            for (int j = 0; j < 8; ++j) {
                float w = Wp[j * 64];
                unsigned short hi = f2b(w);
                uh[j] = hi;
                ul[j] = f2b(w - b2f(hi));
            }
            size_t off = (size_t)l * 12288 + (mm << 12) + XSH(n, kq);
            *(short8*)&whi[off] = *(short8*)uh;
            *(short8*)&wlo[off] = *(short8*)ul;
        }
    } else {
        // ---- embedding gather (bf16) + sorted-graph span boundaries ----
        int idx = (blk - CBLK - WPBLK) * 1024 + t;
        if (idx < N_NODES * 32) {
            int n = idx >> 5, cp = idx & 31;
            const float2 e = *(const float2*)(emb + (((size_t)(node_ids[n] + ID_OFFSET)) << 6) + cp * 2);
            unsigned v = (unsigned)f2b(e.x) | ((unsigned)f2b(e.y) << 16);
            ((unsigned*)h)[n * 32 + cp] = v;
            if (cp == 0) {
                int g = gid[n] & (N_GRAPHS - 1);
                if (n == 0 || (gid[n - 1] & (N_GRAPHS - 1)) != g) gs[g] = n;
                if (n == N_NODES - 1 || (gid[n + 1] & (N_GRAPHS - 1)) != g) ge[g] = n + 1;
            }
        }
    }
}

// ---------------- per-bucket CSR fill (pads rows to a multiple of 16) ----------------

__global__ __launch_bounds__(1024) void fill_kernel(const int* __restrict__ rec,
                                                    const int* __restrict__ cursor,
                                                    int* __restrict__ cnt,
                                                    int* __restrict__ srcs) {
    __shared__ int lcnt[512];
    int t = threadIdx.x;
    int b = blockIdx.x;            // 0..NUSED-1
    if (t < 512) lcnt[t] = 0;
    __syncthreads();
    int nb = cursor[b];
    if (nb < 0) nb = 0;
    if (nb > BCAP) nb = BCAP;
    const int* seg = rec + b * BCAP;
    for (int i = t; i < nb; i += 1024) {
        unsigned r = (unsigned)seg[i];
        int dl = (int)((r >> 17) & 511);
        int s = (int)(r & 0x1FFFF);
        int node = (b << BSHIFT) + dl;
        int p = atomicAdd(&lcnt[dl], 1);
        if (p < CAP && node < N_NODES) srcs[(node << 6) + p] = s;
    }
    __syncthreads();
    if (t < 512) {
        int node = (b << BSHIFT) + t;
        if (node < N_NODES) {
            int deg = lcnt[t];
            cnt[node] = deg;
            int degc = deg > CAP ? CAP : deg;
            int degp = (degc + 15) & ~15;
            if (degp < 16) degp = 16;
            // pad with dummy index -> zeroed row; lets agg run unmasked 16-edge chunks
            for (int p = degc; p < degp; ++p) srcs[(node << 6) + p] = DUMMY_ROW;
        }
    }
}

// ---------------- FUSED GIN layer: gather-aggregate + BN affine + MFMA MLP + pool ----------------
// R1->R2: agg (latency sponge, 0 MFMA) and mlp (MFMA, modest memory) fused. Each wave
// owns its 32 MFMA rows; aggregates them in 4 groups of 8 nodes (64+8 loads in flight
// per burst), applies deferred-BN affine, writes bf16 straight into the swizzled xs
// tile. Deletes the per-layer x round-trip (25.6 MB) and 3 launches; MFMA/pool phases
// of co-resident blocks hide gather latency.

__global__ __launch_bounds__(256) void fused_kernel(const unsigned short* __restrict__ x,
                                                    unsigned short* __restrict__ xo,
                                                    const int* __restrict__ cnt,
                                                    const int* __restrict__ srcs,
                                                    const float* __restrict__ eps, int l,
                                                    float* __restrict__ stats,
                                                    const float* __restrict__ gamma,
                                                    const float* __restrict__ beta,
                                                    const unsigned short* __restrict__ whi,
                                                    const unsigned short* __restrict__ wlo,
                                                    const float* __restrict__ bs,
                                                    const int* __restrict__ graph_ids,
                                                    float* __restrict__ pooled, int last) {
    __shared__ __align__(16) unsigned short xs[128 * 64];    // 16 KB
    __shared__ __align__(16) unsigned short wt[3 * 64 * 64]; // 24 KB (Whi)
    __shared__ int garr[128];
    __shared__ float ssum[256], sqq[256];
    int t = threadIdx.x;
    int nodebase = blockIdx.x * 128;
    int lane = t & 63, w = t >> 6;
    int half = lane >> 5, cl = lane & 31;
    const unsigned* __restrict__ xu = (const unsigned*)x;

    if (lane < 32) {
        int n = nodebase + w * 32 + lane;
        garr[w * 32 + lane] = (n < N_NODES) ? (graph_ids[n] & (N_GRAPHS - 1)) : -1;
    }
    {
        const unsigned short* wsrc = whi + (size_t)l * 12288;
#pragma unroll
        for (int i = 0; i < 6; ++i) {
            int g = i * 256 + t;
            *(int4*)&wt[g * 8] = *(const int4*)&wsrc[g * 8];
        }
    }

    // ---- BN coefficients for layer l-1 (loads issued early, hide under gather)
    float scale = 1.0f + eps[l];
    float a0f = 1.0f, a1f = 1.0f, b0f = 0.0f, b1f = 0.0f;
    if (l > 0) {
        int lp = l - 1;
        float2 sm = *(const float2*)&stats[lp * 128 + 2 * cl];
        float2 sq = *(const float2*)&stats[lp * 128 + 64 + 2 * cl];
        float2 gm = *(const float2*)&gamma[lp * 64 + 2 * cl];
        float2 bt = *(const float2*)&beta[lp * 64 + 2 * cl];
        float mean0 = sm.x * (1.0f / N_NODES);
        float var0 = sq.x * (1.0f / N_NODES) - mean0 * mean0;
        float r0 = rsqrtf(var0 + BN_EPS);
        a0f = gm.x * r0;
        b0f = bt.x - mean0 * a0f;
        float mean1 = sm.y * (1.0f / N_NODES);
        float var1 = sq.y * (1.0f / N_NODES) - mean1 * mean1;
        float r1 = rsqrtf(var1 + BN_EPS);
        a1f = gm.y * r1;
        b1f = bt.y - mean1 * a1f;
    }

    int wb = __builtin_amdgcn_readfirstlane(nodebase + w * 32);

    // ---- gather-aggregate this wave's 32 rows: 4 groups of 8 nodes
    for (int g8 = 0; g8 < 4; ++g8) {
        int nb = wb + g8 * 8;
        int deg[8], degp[8];
        const int* row[8];
#pragma unroll
        for (int n = 0; n < 8; ++n) {
            int d = cnt[nb + n];                       // wave-uniform -> s_load
            int dc = d < 0 ? 0 : (d > CAP ? CAP : d);
            deg[n] = dc;
            int dp = (dc + 15) & ~15;
            degp[n] = dp < 16 ? 16 : dp;
            row[n] = srcs + ((size_t)(nb + n) << 6);
        }
        int cmax = degp[0];
#pragma unroll
        for (int n = 1; n < 8; ++n) cmax = degp[n] > cmax ? degp[n] : cmax;

        unsigned us[8];
#pragma unroll
        for (int n = 0; n < 8; ++n) us[n] = xu[(size_t)(nb + n) * 32 + cl];

        float A0[8], A1[8], B0[8], B1[8];
#pragma unroll
        for (int n = 0; n < 8; ++n) { A0[n] = 0.f; A1[n] = 0.f; B0[n] = 0.f; B1[n] = 0.f; }

        // chunk 0: unconditional (rows padded to >=16) -> 64 gathers in flight
        {
            unsigned uv[8][8];
#pragma unroll
            for (int n = 0; n < 8; ++n)
#pragma unroll
                for (int k = 0; k < 8; ++k) {
                    int ia = row[n][2 * k] & 0x1FFFF;
                    int ib = row[n][2 * k + 1] & 0x1FFFF;
                    int idx = half ? ib : ia;
                    uv[n][k] = xu[(size_t)idx * 32 + cl];
                }
#pragma unroll
            for (int n = 0; n < 8; ++n)
#pragma unroll
                for (int k = 0; k < 8; ++k) {
                    float lo = b2f((unsigned short)(uv[n][k] & 0xFFFF));
                    float hi = b2f((unsigned short)(uv[n][k] >> 16));
                    if (k & 1) { B0[n] += lo; B1[n] += hi; }
                    else       { A0[n] += lo; A1[n] += hi; }
                }
        }
        // remainder chunks: wave-uniform scalar branches, issue-all then consume-all
        for (int c = 16; c < cmax; c += 16) {
            unsigned uc[8][8];
#pragma unroll
            for (int n = 0; n < 8; ++n)
                if (c < degp[n])
#pragma unroll
                    for (int k = 0; k < 8; ++k) {
                        int ia = row[n][c + 2 * k] & 0x1FFFF;
                        int ib = row[n][c + 2 * k + 1] & 0x1FFFF;
                        int idx = half ? ib : ia;
                        uc[n][k] = xu[(size_t)idx * 32 + cl];
                    }
#pragma unroll
            for (int n = 0; n < 8; ++n)
                if (c < degp[n])
#pragma unroll
                    for (int k = 0; k < 8; ++k) {
                        float lo = b2f((unsigned short)(uc[n][k] & 0xFFFF));
                        float hi = b2f((unsigned short)(uc[n][k] >> 16));
                        if (k & 1) { B0[n] += lo; B1[n] += hi; }
                        else       { A0[n] += lo; A1[n] += hi; }
                    }
        }

        // reduce + BN affine + write bf16 into swizzled xs (own rows, no barrier needed)
#pragma unroll
        for (int n = 0; n < 8; ++n) {
            float S0 = A0[n] + B0[n];
            float S1 = A1[n] + B1[n];
            S0 += __shfl_xor(S0, 32);
            S1 += __shfl_xor(S1, 32);
            if (half == 0) {
                float selflo = b2f((unsigned short)(us[n] & 0xFFFF));
                float selfhi = b2f((unsigned short)(us[n] >> 16));
                float db = scale + (float)deg[n];
                float v0 = fmaf(a0f, fmaf(scale, selflo, S0), db * b0f);
                float v1 = fmaf(a1f, fmaf(scale, selfhi, S1), db * b1f);
                int r = w * 32 + g8 * 8 + n;
                int col = 2 * cl;
                *(unsigned*)&xs[XSH(r, col >> 3) + (col & 7)] =
                    (unsigned)f2b(v0) | ((unsigned)f2b(v1) << 16);
            }
        }
    }
    __syncthreads();   // wt staging visible; xs rows are wave-local

    // ---- MFMA MLP (split hi/lo chains, unchanged structure) ----
    int m = lane & 15, q = lane >> 4;
    const float* bb = bs + l * 3 * 64;
    const unsigned short* wlol = wlo + (size_t)l * 12288;
    for (int mm = 0; mm < 3; ++mm) {
        // prefetch lo fragments for this mm (global loads go in flight now)
        short8 bl[2][4];
#pragma unroll
        for (int kc = 0; kc < 2; ++kc)
#pragma unroll
            for (int tj = 0; tj < 4; ++tj)
                bl[kc][tj] = *(const short8*)&wlol[(mm << 12) + XSH(tj * 16 + m, kc * 4 + q)];
        // A fragments (LDS, own rows)
        short8 a[2][2];
#pragma unroll
        for (int kc = 0; kc < 2; ++kc)
#pragma unroll
            for (int ti = 0; ti < 2; ++ti)
                a[kc][ti] = *(const short8*)&xs[XSH(w * 32 + ti * 16 + m, kc * 4 + q)];

        floatx4 acch[2][4], accl[2][4];
#pragma unroll
        for (int tj = 0; tj < 4; ++tj) {
            float bv = bb[mm * 64 + tj * 16 + m];
#pragma unroll
            for (int ti = 0; ti < 2; ++ti) {
                acch[ti][tj] = (floatx4){bv, bv, bv, bv};
                accl[ti][tj] = (floatx4){0.f, 0.f, 0.f, 0.f};
            }
        }
        // hi chain: LDS-only dependencies, 16 back-to-back MFMAs
#pragma unroll
        for (int kc = 0; kc < 2; ++kc) {
            short8 bh[4];
#pragma unroll
            for (int tj = 0; tj < 4; ++tj)
                bh[tj] = *(const short8*)&wt[(mm << 12) + XSH(tj * 16 + m, kc * 4 + q)];
#pragma unroll
            for (int ti = 0; ti < 2; ++ti)
#pragma unroll
                for (int tj = 0; tj < 4; ++tj)
                    acch[ti][tj] = __builtin_amdgcn_mfma_f32_16x16x32_bf16(a[kc][ti], bh[tj], acch[ti][tj], 0, 0, 0);
        }
        // lo chain: consumes the prefetched (now-arrived) bl fragments
#pragma unroll
        for (int kc = 0; kc < 2; ++kc)
#pragma unroll
            for (int ti = 0; ti < 2; ++ti)
#pragma unroll
                for (int tj = 0; tj < 4; ++tj)
                    accl[ti][tj] = __builtin_amdgcn_mfma_f32_16x16x32_bf16(a[kc][ti], bl[kc][tj], accl[ti][tj], 0, 0, 0);
        // combine + ReLU + write-back (wave-local rows)
#pragma unroll
        for (int ti = 0; ti < 2; ++ti)
#pragma unroll
            for (int tj = 0; tj < 4; ++tj) {
                int col = tj * 16 + m;
#pragma unroll
                for (int r = 0; r < 4; ++r) {
                    int row = w * 32 + ti * 16 + q * 4 + r;
                    float v = acch[ti][tj][r] + accl[ti][tj][r];
                    xs[XSH(row, col >> 3) + (col & 7)] = f2b(v > 0.f ? v : 0.f);
                }
            }
    }

    if (!last) {
        unsigned* xou = (unsigned*)xo;
#pragma unroll
        for (int it = 0; it < 16; ++it) {
            int row = w * 32 + (lane >> 5) + it * 2;
            int cp = lane & 31;
            int col = cp * 2;
            unsigned val = *(const unsigned*)&xs[XSH(row, col >> 3) + (col & 7)];
            int node = nodebase + row;
            if (node < N_NODES) xou[(size_t)node * 32 + cp] = val;
        }
    }
    {
        int c = lane;
        float s = 0.f, q2 = 0.f, acc2 = 0.f;
        int cur = -1;
        for (int k = 0; k < 32; ++k) {
            int row = w * 32 + k;
            int g = garr[row];
            if (g >= 0) {
                float v = b2f(xs[XSH(row, c >> 3) + (c & 7)]);
                s += v;
                q2 += v * v;
                if (g != cur) {
                    if (cur >= 0) atomicAdd(&pooled[cur * 192 + l * 64 + c], acc2);
                    acc2 = 0.f;
                    cur = g;
                }
                acc2 += v;
            }
        }
        if (cur >= 0) atomicAdd(&pooled[cur * 192 + l * 64 + c], acc2);
        ssum[t] = s;
        sqq[t] = q2;
    }
    __syncthreads();
    if (t < 64) {
        float S = ssum[t] + ssum[t + 64] + ssum[t + 128] + ssum[t + 192];
        float Q = sqq[t] + sqq[t + 64] + sqq[t + 128] + sqq[t + 192];
        atomicAdd(&stats[l * 128 + t], S);
        atomicAdd(&stats[l * 128 + 64 + t], Q);
    }
}

// ---------------- final classifier ----------------

__global__ __launch_bounds__(256) void out_kernel(const float* __restrict__ pooled,
                                                  const float* __restrict__ stats,
                                                  const float* __restrict__ gamma,
                                                  const float* __restrict__ beta,
                                                  const int* __restrict__ gs,
                                                  const int* __restrict__ ge,
                                                  const float* __restrict__ Wo,
                                                  const float* __restrict__ bo,
                                                  float* __restrict__ out) {
    __shared__ float sab[384];
    int t = threadIdx.x;
    if (t < 192) {
        int l2 = t / 64, c = t & 63;
        float mean = stats[l2 * 128 + c] * (1.0f / N_NODES);
        float var = stats[l2 * 128 + 64 + c] * (1.0f / N_NODES) - mean * mean;
        float rstd = rsqrtf(var + BN_EPS);
        float a = gamma[l2 * 64 + c] * rstd;
        sab[l2 * 128 + c] = a;
        sab[l2 * 128 + 64 + c] = beta[l2 * 64 + c] - mean * a;
    }
    __syncthreads();
    int idx = blockIdx.x * blockDim.x + t;
    if (idx < N_GRAPHS * NUM_CLASSES) {
        int g = idx / NUM_CLASSES, k = idx % NUM_CLASSES;
        float cg = (float)(ge[g] - gs[g]);
        float acc = bo[k];
        for (int l2 = 0; l2 < 3; ++l2)
            for (int c = 0; c < 64; ++c) {
                float gf = fmaf(sab[l2 * 128 + c], pooled[g * 192 + l2 * 64 + c],
                                sab[l2 * 128 + 64 + c] * cg);
                acc = fmaf(gf, Wo[(l2 * 64 + c) * NUM_CLASSES + k], acc);
            }
        out[idx] = acc;
    }
}

extern "C" void kernel_launch(void* const* d_in, const int* in_sizes, int n_in,
                              void* d_out, int out_size, void* d_ws, size_t ws_size,
                              hipStream_t stream) {
    const int*   node_ids  = (const int*)d_in[0];
    const int*   edge_src  = (const int*)d_in[1];
    const int*   edge_dst  = (const int*)d_in[2];
    const int*   graph_ids = (const int*)d_in[3];
    const float* emb       = (const float*)d_in[4];
    const float* Ws        = (const float*)d_in[5];
    const float* bs        = (const float*)d_in[6];
    const float* gamma     = (const float*)d_in[7];
    const float* beta      = (const float*)d_in[8];
    const float* eps       = (const float*)d_in[9];
    const float* W_out     = (const float*)d_in[10];
    const float* b_out     = (const float*)d_in[11];
    float* out = (float*)d_out;

    // workspace
    unsigned short* h    = (unsigned short*)d_ws;         // 6,400,000 sh (+8192 slack)
    unsigned short* xin  = h + 6400000 + 8192;            // 6,400,000 sh (+8192 slack)
    unsigned short* whi  = xin + 6400000 + 8192;          // 36,864 sh
    unsigned short* wlo  = whi + 36864;                   // 36,864 sh
    int*   srcs   = (int*)(wlo + 36864);                  // 6,400,000 i (padded CSR)
    int*   rec    = srcs + 6400000;                       // NUSED*BCAP i
    float* pooled = (float*)(rec + NUSED * BCAP);         // 98,304 f
    float* stats  = pooled + 98304;                       // 384 f
    int*   cnt    = (int*)(stats + 384);                  // 100,000 i
    int*   gs     = cnt + 100000;                         // 512 i
    int*   ge     = gs + 512;                             // 512 i
    int*   cursor = ge + 512;                             // 256 i (bucket totals)

    hipMemsetAsync(pooled, 0,
                   (size_t)(98304 + 384 + 100000 + 512 + 512 + 256) * 4, stream);
    // zero the DUMMY_ROW (row 100000) in both x buffers: pad-gather target
    hipMemsetAsync(h + (size_t)DUMMY_ROW * 64, 0, 128, stream);
    hipMemsetAsync(xin + (size_t)DUMMY_ROW * 64, 0, 128, stream);

    prep_kernel<<<CBLK + WPBLK + EMBBLK, 1024, 0, stream>>>(
        edge_src, edge_dst, cursor, rec, Ws, whi, wlo,
        node_ids, graph_ids, emb, h, gs, ge);
    fill_kernel<<<NUSED, 1024, 0, stream>>>(rec, cursor, cnt, srcs);

    const int FUSE_BLK = (N_NODES + 127) / 128;   // 782
    for (int l = 0; l < 3; ++l) {
        const unsigned short* X = (l % 2 == 0) ? h : xin;   // gather source
        unsigned short* A = (l % 2 == 0) ? xin : h;         // this-layer output
        fused_kernel<<<FUSE_BLK, 256, 0, stream>>>(
            X, A, cnt, srcs, eps, l, stats, gamma, beta,
            whi, wlo, bs, graph_ids, pooled, l == 2);
    }

    out_kernel<<<(N_GRAPHS * NUM_CLASSES + 255) / 256, 256, 0, stream>>>(
        pooled, stats, gamma, beta, gs, ge, W_out, b_out, out);
}

// Round 3
// 339.938 us; speedup vs baseline: 1.9372x; 1.9372x over previous
//
#include <hip/hip_runtime.h>

#define N_NODES 100000
#define N_EDGES 1600000
#define N_GRAPHS 512
#define HID 64
#define NUM_CLASSES 100
#define ID_OFFSET 1500
#define BN_EPS 1e-5f
#define CAP 64
#define NBKT 256
#define BSHIFT 9
#define NUSED ((N_NODES + 511) >> 9)   // 196 buckets of 512 nodes
#define BCAP 10240                      // per-bucket record capacity
#define CBLK 98
#define CHUNK 16384
#define WPBLK 5                         // wprep blocks inside prep_kernel
#define EMBBLK ((N_NODES * 32 + 1023) / 1024)   // 3125
#define DUMMY_ROW 100000                // zeroed row in x-buffer slack, pad target

typedef __attribute__((ext_vector_type(8))) short short8;
typedef __attribute__((ext_vector_type(4))) float floatx4;

__device__ __forceinline__ float b2f(unsigned short u) {
    return __builtin_bit_cast(float, ((unsigned)u) << 16);
}
__device__ __forceinline__ unsigned short f2b(float f) {   // RNE
    unsigned x = __builtin_bit_cast(unsigned, f);
    x += 0x7FFFu + ((x >> 16) & 1u);
    return (unsigned short)(x >> 16);
}

// swizzled granule layout: 16-row tiles, 8 granules(16B)/row, granule slot = (row&15)^q
#define XSH(row, qq) ((((((row) >> 4) << 7) + ((qq) << 4) + (((row) & 15) ^ (qq))) * 8))

// ---------------- fused prep: direct-binning build + wprep + embed in one launch ----------------

__global__ __launch_bounds__(1024) void prep_kernel(const int* __restrict__ src,
                                                    const int* __restrict__ dst,
                                                    int* __restrict__ cursor,
                                                    int* __restrict__ rec,
                                                    const float* __restrict__ Ws,
                                                    unsigned short* __restrict__ whi,
                                                    unsigned short* __restrict__ wlo,
                                                    const int* __restrict__ node_ids,
                                                    const int* __restrict__ gid,
                                                    const float* __restrict__ emb,
                                                    unsigned short* __restrict__ h,
                                                    int* __restrict__ gs,
                                                    int* __restrict__ ge) {
    __shared__ int hist[NBKT];
    __shared__ int base_s[NBKT];
    int t = threadIdx.x;
    int blk = blockIdx.x;

    if (blk < CBLK) {
        // ---- edge binning (one pass) ----
        if (t < NBKT) hist[t] = 0;
        __syncthreads();
        int cb = blk * CHUNK;
        int d_[16], s_[16];
#pragma unroll
        for (int k = 0; k < 16; ++k) {
            int i = cb + k * 1024 + t;
            d_[k] = (i < N_EDGES) ? dst[i] : -1;
            s_[k] = (i < N_EDGES) ? src[i] : 0;
            if (d_[k] >= 0) atomicAdd(&hist[((unsigned)d_[k] >> BSHIFT) & (NBKT - 1)], 1);
        }
        __syncthreads();
        if (t < NBKT) base_s[t] = (hist[t] > 0) ? atomicAdd(&cursor[t], hist[t]) : 0;
        __syncthreads();
        if (t < NBKT) hist[t] = 0;
        __syncthreads();
#pragma unroll
        for (int k = 0; k < 16; ++k) {
            if (d_[k] >= 0) {
                unsigned d = (unsigned)d_[k];
                int b = (d >> BSHIFT) & (NBKT - 1);
                int p = atomicAdd(&hist[b], 1);
                int g = base_s[b] + p;
                if ((unsigned)g < BCAP)
                    rec[b * BCAP + g] = ((int)(d & 511) << 17) | (s_[k] & 0x1FFFF);
            }
        }
    } else if (blk < CBLK + WPBLK) {
        // ---- W pre-convert + pre-swizzle, hi/lo split ----
        int G = (blk - CBLK) * 1024 + t;
        if (G < 3 * 1536) {
            int l = G / 1536, Gp = G % 1536;
            int mm = Gp >> 9, rem = Gp & 511;
            int kq = rem >> 6, n = rem & 63;
            const float* Wp = Ws + l * 12288 + mm * 4096 + (kq * 8) * 64 + n;
            unsigned short uh[8], ul[8];
#pragma unroll
            for (int j = 0; j < 8; ++j) {
                float w = Wp[j * 64];
                unsigned short hi = f2b(w);
                uh[j] = hi;
                ul[j] = f2b(w - b2f(hi));
            }
            size_t off = (size_t)l * 12288 + (mm << 12) + XSH(n, kq);
            *(short8*)&whi[off] = *(short8*)uh;
            *(short8*)&wlo[off] = *(short8*)ul;
        }
    } else {
        // ---- embedding gather (bf16) + sorted-graph span boundaries ----
        int idx = (blk - CBLK - WPBLK) * 1024 + t;
        if (idx < N_NODES * 32) {
            int n = idx >> 5, cp = idx & 31;
            const float2 e = *(const float2*)(emb + (((size_t)(node_ids[n] + ID_OFFSET)) << 6) + cp * 2);
            unsigned v = (unsigned)f2b(e.x) | ((unsigned)f2b(e.y) << 16);
            ((unsigned*)h)[n * 32 + cp] = v;
            if (cp == 0) {
                int g = gid[n] & (N_GRAPHS - 1);
                if (n == 0 || (gid[n - 1] & (N_GRAPHS - 1)) != g) gs[g] = n;
                if (n == N_NODES - 1 || (gid[n + 1] & (N_GRAPHS - 1)) != g) ge[g] = n + 1;
            }
        }
    }
}

// ---------------- per-bucket CSR fill (pads rows to a multiple of 16) ----------------

__global__ __launch_bounds__(1024) void fill_kernel(const int* __restrict__ rec,
                                                    const int* __restrict__ cursor,
                                                    int* __restrict__ cnt,
                                                    int* __restrict__ srcs) {
    __shared__ int lcnt[512];
    int t = threadIdx.x;
    int b = blockIdx.x;            // 0..NUSED-1
    if (t < 512) lcnt[t] = 0;
    __syncthreads();
    int nb = cursor[b];
    if (nb < 0) nb = 0;
    if (nb > BCAP) nb = BCAP;
    const int* seg = rec + b * BCAP;
    for (int i = t; i < nb; i += 1024) {
        unsigned r = (unsigned)seg[i];
        int dl = (int)((r >> 17) & 511);
        int s = (int)(r & 0x1FFFF);
        int node = (b << BSHIFT) + dl;
        int p = atomicAdd(&lcnt[dl], 1);
        if (p < CAP && node < N_NODES) srcs[(node << 6) + p] = s;
    }
    __syncthreads();
    if (t < 512) {
        int node = (b << BSHIFT) + t;
        if (node < N_NODES) {
            int deg = lcnt[t];
            cnt[node] = deg;
            int degc = deg > CAP ? CAP : deg;
            int degp = (degc + 15) & ~15;
            if (degp < 16) degp = 16;
            // pad with dummy index -> zeroed row; lets agg run unmasked 16-edge chunks
            for (int p = degc; p < degp; ++p) srcs[(node << 6) + p] = DUMMY_ROW;
        }
    }
}

// ---------------- GIN aggregation (R1 version: 4 nodes/wave, batched latency chain) ----------------
// Near its floor: 89 MB L2-miss traffic == 8-XCD compulsory minimum (8 x 12.8 MB),
// moving at the ~2.2-2.6 TB/s random-128B fabric ceiling. Frozen.

__global__ __launch_bounds__(256) void agg_kernel(const unsigned short* __restrict__ x,
                                                  const int* __restrict__ cnt,
                                                  const int* __restrict__ srcs,
                                                  const float* __restrict__ eps, int l,
                                                  const float* __restrict__ stats,
                                                  const float* __restrict__ gamma,
                                                  const float* __restrict__ beta,
                                                  unsigned short* __restrict__ out) {
    int nb = __builtin_amdgcn_readfirstlane(((blockIdx.x << 2) + (threadIdx.x >> 6)) << 2);
    int lane = threadIdx.x & 63;
    int half = lane >> 5;
    int cl = lane & 31;
    const unsigned* __restrict__ xu = (const unsigned*)x;

    // ---- BN coefficients for layer l-1, prefetched early (latency hides under gathers)
    float scale = 1.0f + eps[l];
    float a0f = 1.0f, a1f = 1.0f, b0f = 0.0f, b1f = 0.0f;
    if (l > 0) {
        int lp = l - 1;
        float2 sm = *(const float2*)&stats[lp * 128 + 2 * cl];
        float2 sq = *(const float2*)&stats[lp * 128 + 64 + 2 * cl];
        float2 gm = *(const float2*)&gamma[lp * 64 + 2 * cl];
        float2 bt = *(const float2*)&beta[lp * 64 + 2 * cl];
        float mean0 = sm.x * (1.0f / N_NODES);
        float var0 = sq.x * (1.0f / N_NODES) - mean0 * mean0;
        float r0 = rsqrtf(var0 + BN_EPS);
        a0f = gm.x * r0;
        b0f = bt.x - mean0 * a0f;
        float mean1 = sm.y * (1.0f / N_NODES);
        float var1 = sq.y * (1.0f / N_NODES) - mean1 * mean1;
        float r1 = rsqrtf(var1 + BN_EPS);
        a1f = gm.y * r1;
        b1f = bt.y - mean1 * a1f;
    }

    // ---- degrees + row pointers for 4 consecutive nodes (scalar loads)
    int deg[4], degp[4];
    const int* row[4];
#pragma unroll
    for (int n = 0; n < 4; ++n) {
        int d = cnt[nb + n];
        int dc = d < 0 ? 0 : (d > CAP ? CAP : d);
        deg[n] = dc;
        int dp = (dc + 15) & ~15;
        degp[n] = dp < 16 ? 16 : dp;
        row[n] = srcs + ((size_t)(nb + n) << 6);
    }
    int cmax = degp[0];
    cmax = degp[1] > cmax ? degp[1] : cmax;
    cmax = degp[2] > cmax ? degp[2] : cmax;
    cmax = degp[3] > cmax ? degp[3] : cmax;

    // ---- self rows (issued alongside the gather burst)
    unsigned us[4];
#pragma unroll
    for (int n = 0; n < 4; ++n) us[n] = xu[(size_t)(nb + n) * 32 + cl];

    float A0[4] = {0.f, 0.f, 0.f, 0.f}, A1[4] = {0.f, 0.f, 0.f, 0.f};
    float B0[4] = {0.f, 0.f, 0.f, 0.f}, B1[4] = {0.f, 0.f, 0.f, 0.f};

    // ---- chunk 0: unconditional for all 4 nodes (rows padded to >=16), 32 loads in flight
    {
        unsigned uv[4][8];
#pragma unroll
        for (int n = 0; n < 4; ++n)
#pragma unroll
            for (int k = 0; k < 8; ++k) {
                int ia = row[n][2 * k] & 0x1FFFF;
                int ib = row[n][2 * k + 1] & 0x1FFFF;
                int idx = half ? ib : ia;
                uv[n][k] = xu[(size_t)idx * 32 + cl];
            }
#pragma unroll
        for (int n = 0; n < 4; ++n)
#pragma unroll
            for (int k = 0; k < 8; ++k) {
                float lo = b2f((unsigned short)(uv[n][k] & 0xFFFF));
                float hi = b2f((unsigned short)(uv[n][k] >> 16));
                if (k & 1) { B0[n] += lo; B1[n] += hi; }
                else       { A0[n] += lo; A1[n] += hi; }
            }
    }

    // ---- remainder chunks: wave-uniform scalar branches, issue-all then consume-all
    for (int c = 16; c < cmax; c += 16) {
        unsigned uc[4][8];
#pragma unroll
        for (int n = 0; n < 4; ++n)
            if (c < degp[n])
#pragma unroll
                for (int k = 0; k < 8; ++k) {
                    int ia = row[n][c + 2 * k] & 0x1FFFF;
                    int ib = row[n][c + 2 * k + 1] & 0x1FFFF;
                    int idx = half ? ib : ia;
                    uc[n][k] = xu[(size_t)idx * 32 + cl];
                }
#pragma unroll
        for (int n = 0; n < 4; ++n)
            if (c < degp[n])
#pragma unroll
                for (int k = 0; k < 8; ++k) {
                    float lo = b2f((unsigned short)(uc[n][k] & 0xFFFF));
                    float hi = b2f((unsigned short)(uc[n][k] >> 16));
                    if (k & 1) { B0[n] += lo; B1[n] += hi; }
                    else       { A0[n] += lo; A1[n] += hi; }
                }
    }

    // ---- reduce + BN affine + pack
#pragma unroll
    for (int n = 0; n < 4; ++n) {
        float S0 = (A0[n] + B0[n]);
        float S1 = (A1[n] + B1[n]);
        S0 += __shfl_xor(S0, 32);
        S1 += __shfl_xor(S1, 32);
        if (half == 0) {
            float selflo = b2f((unsigned short)(us[n] & 0xFFFF));
            float selfhi = b2f((unsigned short)(us[n] >> 16));
            float db = scale + (float)deg[n];
            float v0 = fmaf(a0f, fmaf(scale, selflo, S0), db * b0f);
            float v1 = fmaf(a1f, fmaf(scale, selfhi, S1), db * b1f);
            ((unsigned*)out)[(size_t)(nb + n) * 32 + cl] =
                (unsigned)f2b(v0) | ((unsigned)f2b(v1) << 16);
        }
    }
}

// ---------------- MFMA MLP v5: occupancy-first ----------------
// R2 diagnosis: mlp was ~41 us/dispatch at ~2 blocks/CU (43.5 KB LDS: 24 KB of it the
// Whi stage; 136 VGPR). Fix: (1) drop wt LDS entirely -- hi fragments load from global
// whi (74 KB, L2/L1-hot) like lo already does; LDS 43.5->18.9 KB. (2) single accumulator
// (bias + hi chain + lo chain on same acc) saves 32 VGPR -> ~108 peak, launch_bounds
// (256,4) pins <=128 -> 16 waves/CU VGPR-wise. (3) first barrier deleted (xs rows,
// garr are wave-private; it only ordered the wt stage).

__global__ __launch_bounds__(256, 4) void mlp_kernel(unsigned short* __restrict__ x,
                                                     const unsigned short* __restrict__ whi,
                                                     const unsigned short* __restrict__ wlo,
                                                     const float* __restrict__ bs, int l,
                                                     float* __restrict__ stats,
                                                     const int* __restrict__ graph_ids,
                                                     float* __restrict__ pooled, int last) {
    __shared__ __align__(16) unsigned short xs[128 * 64];    // 16 KB
    __shared__ int garr[128];
    __shared__ float ssum[256], sqq[256];
    int t = threadIdx.x;
    int nodebase = blockIdx.x * 128;
    int lane = t & 63, w = t >> 6;

    if (lane < 32) {
        int n = nodebase + w * 32 + lane;
        garr[w * 32 + lane] = (n < N_NODES) ? (graph_ids[n] & (N_GRAPHS - 1)) : -1;
    }
#pragma unroll
    for (int i = 0; i < 4; ++i) {
        int g = i * 64 + lane;
        int rl = g >> 3, qr = g & 7;
        int row = w * 32 + rl;
        const int4 v = *(const int4*)(x + (((size_t)(nodebase + row)) << 6) + qr * 8);
        *(int4*)&xs[XSH(row, qr)] = v;
    }
    // no barrier: xs rows and garr entries are wave-private until the stats reduce

    int m = lane & 15, q = lane >> 4;
    const float* bb = bs + l * 3 * 64;
    const unsigned short* whil = whi + (size_t)l * 12288;
    const unsigned short* wlol = wlo + (size_t)l * 12288;
    for (int mm = 0; mm < 3; ++mm) {
        // prefetch lo fragments for this mm (global loads go in flight now)
        short8 bl[2][4];
#pragma unroll
        for (int kc = 0; kc < 2; ++kc)
#pragma unroll
            for (int tj = 0; tj < 4; ++tj)
                bl[kc][tj] = *(const short8*)&wlol[(mm << 12) + XSH(tj * 16 + m, kc * 4 + q)];
        // A fragments (LDS, own rows)
        short8 a[2][2];
#pragma unroll
        for (int kc = 0; kc < 2; ++kc)
#pragma unroll
            for (int ti = 0; ti < 2; ++ti)
                a[kc][ti] = *(const short8*)&xs[XSH(w * 32 + ti * 16 + m, kc * 4 + q)];

        floatx4 acc[2][4];
#pragma unroll
        for (int tj = 0; tj < 4; ++tj) {
            float bv = bb[mm * 64 + tj * 16 + m];
#pragma unroll
            for (int ti = 0; ti < 2; ++ti)
                acc[ti][tj] = (floatx4){bv, bv, bv, bv};
        }
        // hi chain: 16 MFMAs, bh fragments straight from global (L1/L2-hot)
#pragma unroll
        for (int kc = 0; kc < 2; ++kc) {
            short8 bh[4];
#pragma unroll
            for (int tj = 0; tj < 4; ++tj)
                bh[tj] = *(const short8*)&whil[(mm << 12) + XSH(tj * 16 + m, kc * 4 + q)];
#pragma unroll
            for (int ti = 0; ti < 2; ++ti)
#pragma unroll
                for (int tj = 0; tj < 4; ++tj)
                    acc[ti][tj] = __builtin_amdgcn_mfma_f32_16x16x32_bf16(a[kc][ti], bh[tj], acc[ti][tj], 0, 0, 0);
        }
        // lo chain: same accumulator, consumes the prefetched bl fragments
#pragma unroll
        for (int kc = 0; kc < 2; ++kc)
#pragma unroll
            for (int ti = 0; ti < 2; ++ti)
#pragma unroll
                for (int tj = 0; tj < 4; ++tj)
                    acc[ti][tj] = __builtin_amdgcn_mfma_f32_16x16x32_bf16(a[kc][ti], bl[kc][tj], acc[ti][tj], 0, 0, 0);
        // ReLU + write-back (wave-local rows)
#pragma unroll
        for (int ti = 0; ti < 2; ++ti)
#pragma unroll
            for (int tj = 0; tj < 4; ++tj) {
                int col = tj * 16 + m;
#pragma unroll
                for (int r = 0; r < 4; ++r) {
                    int row = w * 32 + ti * 16 + q * 4 + r;
                    float v = acc[ti][tj][r];
                    xs[XSH(row, col >> 3) + (col & 7)] = f2b(v > 0.f ? v : 0.f);
                }
            }
    }

    if (!last) {
        unsigned* xo = (unsigned*)x;
#pragma unroll
        for (int it = 0; it < 16; ++it) {
            int row = w * 32 + (lane >> 5) + it * 2;
            int cp = lane & 31;
            int col = cp * 2;
            unsigned val = *(const unsigned*)&xs[XSH(row, col >> 3) + (col & 7)];
            int node = nodebase + row;
            if (node < N_NODES) xo[(size_t)node * 32 + cp] = val;
        }
    }
    {
        int c = lane;
        float s = 0.f, q2 = 0.f, acc2 = 0.f;
        int cur = -1;
        for (int k = 0; k < 32; ++k) {
            int row = w * 32 + k;
            int g = garr[row];
            if (g >= 0) {
                float v = b2f(xs[XSH(row, c >> 3) + (c & 7)]);
                s += v;
                q2 += v * v;
                if (g != cur) {
                    if (cur >= 0) atomicAdd(&pooled[cur * 192 + l * 64 + c], acc2);
                    acc2 = 0.f;
                    cur = g;
                }
                acc2 += v;
            }
        }
        if (cur >= 0) atomicAdd(&pooled[cur * 192 + l * 64 + c], acc2);
        ssum[t] = s;
        sqq[t] = q2;
    }
    __syncthreads();
    if (t < 64) {
        float S = ssum[t] + ssum[t + 64] + ssum[t + 128] + ssum[t + 192];
        float Q = sqq[t] + sqq[t + 64] + sqq[t + 128] + sqq[t + 192];
        atomicAdd(&stats[l * 128 + t], S);
        atomicAdd(&stats[l * 128 + 64 + t], Q);
    }
}

// ---------------- final classifier ----------------

__global__ __launch_bounds__(256) void out_kernel(const float* __restrict__ pooled,
                                                  const float* __restrict__ stats,
                                                  const float* __restrict__ gamma,
                                                  const float* __restrict__ beta,
                                                  const int* __restrict__ gs,
                                                  const int* __restrict__ ge,
                                                  const float* __restrict__ Wo,
                                                  const float* __restrict__ bo,
                                                  float* __restrict__ out) {
    __shared__ float sab[384];
    int t = threadIdx.x;
    if (t < 192) {
        int l2 = t / 64, c = t & 63;
        float mean = stats[l2 * 128 + c] * (1.0f / N_NODES);
        float var = stats[l2 * 128 + 64 + c] * (1.0f / N_NODES) - mean * mean;
        float rstd = rsqrtf(var + BN_EPS);
        float a = gamma[l2 * 64 + c] * rstd;
        sab[l2 * 128 + c] = a;
        sab[l2 * 128 + 64 + c] = beta[l2 * 64 + c] - mean * a;
    }
    __syncthreads();
    int idx = blockIdx.x * blockDim.x + t;
    if (idx < N_GRAPHS * NUM_CLASSES) {
        int g = idx / NUM_CLASSES, k = idx % NUM_CLASSES;
        float cg = (float)(ge[g] - gs[g]);
        float acc = bo[k];
        for (int l2 = 0; l2 < 3; ++l2)
            for (int c = 0; c < 64; ++c) {
                float gf = fmaf(sab[l2 * 128 + c], pooled[g * 192 + l2 * 64 + c],
                                sab[l2 * 128 + 64 + c] * cg);
                acc = fmaf(gf, Wo[(l2 * 64 + c) * NUM_CLASSES + k], acc);
            }
        out[idx] = acc;
    }
}

extern "C" void kernel_launch(void* const* d_in, const int* in_sizes, int n_in,
                              void* d_out, int out_size, void* d_ws, size_t ws_size,
                              hipStream_t stream) {
    const int*   node_ids  = (const int*)d_in[0];
    const int*   edge_src  = (const int*)d_in[1];
    const int*   edge_dst  = (const int*)d_in[2];
    const int*   graph_ids = (const int*)d_in[3];
    const float* emb       = (const float*)d_in[4];
    const float* Ws        = (const float*)d_in[5];
    const float* bs        = (const float*)d_in[6];
    const float* gamma     = (const float*)d_in[7];
    const float* beta      = (const float*)d_in[8];
    const float* eps       = (const float*)d_in[9];
    const float* W_out     = (const float*)d_in[10];
    const float* b_out     = (const float*)d_in[11];
    float* out = (float*)d_out;

    // workspace
    unsigned short* h    = (unsigned short*)d_ws;         // 6,400,000 sh (+8192 slack)
    unsigned short* xin  = h + 6400000 + 8192;            // 6,400,000 sh (+8192 slack)
    unsigned short* whi  = xin + 6400000 + 8192;          // 36,864 sh
    unsigned short* wlo  = whi + 36864;                   // 36,864 sh
    int*   srcs   = (int*)(wlo + 36864);                  // 6,400,000 i (padded CSR)
    int*   rec    = srcs + 6400000;                       // NUSED*BCAP i
    float* pooled = (float*)(rec + NUSED * BCAP);         // 98,304 f
    float* stats  = pooled + 98304;                       // 384 f
    int*   cnt    = (int*)(stats + 384);                  // 100,000 i
    int*   gs     = cnt + 100000;                         // 512 i
    int*   ge     = gs + 512;                             // 512 i
    int*   cursor = ge + 512;                             // 256 i (bucket totals)

    hipMemsetAsync(pooled, 0,
                   (size_t)(98304 + 384 + 100000 + 512 + 512 + 256) * 4, stream);
    // zero the DUMMY_ROW (row 100000) in both x buffers: pad-gather target
    hipMemsetAsync(h + (size_t)DUMMY_ROW * 64, 0, 128, stream);
    hipMemsetAsync(xin + (size_t)DUMMY_ROW * 64, 0, 128, stream);

    prep_kernel<<<CBLK + WPBLK + EMBBLK, 1024, 0, stream>>>(
        edge_src, edge_dst, cursor, rec, Ws, whi, wlo,
        node_ids, graph_ids, emb, h, gs, ge);
    fill_kernel<<<NUSED, 1024, 0, stream>>>(rec, cursor, cnt, srcs);

    const int MLP_BLK = (N_NODES + 127) / 128;   // 782
    const int AGG_BLK = N_NODES / 16;            // 6250 blocks * 4 waves * 4 nodes
    for (int l = 0; l < 3; ++l) {
        unsigned short* X = (l % 2 == 0) ? h : xin;
        unsigned short* A = (l % 2 == 0) ? xin : h;
        agg_kernel<<<AGG_BLK, 256, 0, stream>>>(X, cnt, srcs, eps, l, stats, gamma, beta, A);
        mlp_kernel<<<MLP_BLK, 256, 0, stream>>>(A, whi, wlo, bs, l, stats, graph_ids, pooled, l == 2);
    }

    out_kernel<<<(N_GRAPHS * NUM_CLASSES + 255) / 256, 256, 0, stream>>>(
        pooled, stats, gamma, beta, gs, ge, W_out, b_out, out);
}

// Round 4
// 334.338 us; speedup vs baseline: 1.9696x; 1.0167x over previous
//
#include <hip/hip_runtime.h>

#define N_NODES 100000
#define N_EDGES 1600000
#define N_GRAPHS 512
#define HID 64
#define NUM_CLASSES 100
#define ID_OFFSET 1500
#define BN_EPS 1e-5f
#define CAP 64
#define NBKT 256
#define BSHIFT 9
#define NUSED ((N_NODES + 511) >> 9)   // 196 buckets of 512 nodes
#define BCAP 10240                      // per-bucket record capacity
#define CBLK 98
#define CHUNK 16384
#define WPBLK 5                         // wprep blocks inside prep_kernel
#define EMBBLK ((N_NODES * 32 + 1023) / 1024)   // 3125
#define DUMMY_ROW 100000                // zeroed row in x-buffer slack, pad target

typedef __attribute__((ext_vector_type(8))) short short8;
typedef __attribute__((ext_vector_type(4))) float floatx4;

__device__ __forceinline__ float b2f(unsigned short u) {
    return __builtin_bit_cast(float, ((unsigned)u) << 16);
}
__device__ __forceinline__ unsigned short f2b(float f) {   // RNE
    unsigned x = __builtin_bit_cast(unsigned, f);
    x += 0x7FFFu + ((x >> 16) & 1u);
    return (unsigned short)(x >> 16);
}

// swizzled granule layout: 16-row tiles, 8 granules(16B)/row, granule slot = (row&15)^q
#define XSH(row, qq) ((((((row) >> 4) << 7) + ((qq) << 4) + (((row) & 15) ^ (qq))) * 8))

// ---------------- fused prep: binning + wprep + embed + dummy-row zero ----------------

__global__ __launch_bounds__(1024) void prep_kernel(const int* __restrict__ src,
                                                    const int* __restrict__ dst,
                                                    int* __restrict__ cursor,
                                                    int* __restrict__ rec,
                                                    const float* __restrict__ Ws,
                                                    unsigned short* __restrict__ whi,
                                                    unsigned short* __restrict__ wlo,
                                                    const int* __restrict__ node_ids,
                                                    const int* __restrict__ gid,
                                                    const float* __restrict__ emb,
                                                    unsigned short* __restrict__ h,
                                                    unsigned short* __restrict__ xin,
                                                    int* __restrict__ gs,
                                                    int* __restrict__ ge) {
    __shared__ int hist[NBKT];
    __shared__ int base_s[NBKT];
    int t = threadIdx.x;
    int blk = blockIdx.x;

    if (blk < CBLK) {
        // ---- dummy-row zeroing piggybacked on block 0 (replaces 2 memset launches)
        if (blk == 0 && t < 32) {
            ((unsigned*)(h + (size_t)DUMMY_ROW * 64))[t] = 0u;
            ((unsigned*)(xin + (size_t)DUMMY_ROW * 64))[t] = 0u;
        }
        // ---- edge binning (one pass) ----
        if (t < NBKT) hist[t] = 0;
        __syncthreads();
        int cb = blk * CHUNK;
        int d_[16], s_[16];
#pragma unroll
        for (int k = 0; k < 16; ++k) {
            int i = cb + k * 1024 + t;
            d_[k] = (i < N_EDGES) ? dst[i] : -1;
            s_[k] = (i < N_EDGES) ? src[i] : 0;
            if (d_[k] >= 0) atomicAdd(&hist[((unsigned)d_[k] >> BSHIFT) & (NBKT - 1)], 1);
        }
        __syncthreads();
        if (t < NBKT) base_s[t] = (hist[t] > 0) ? atomicAdd(&cursor[t], hist[t]) : 0;
        __syncthreads();
        if (t < NBKT) hist[t] = 0;
        __syncthreads();
#pragma unroll
        for (int k = 0; k < 16; ++k) {
            if (d_[k] >= 0) {
                unsigned d = (unsigned)d_[k];
                int b = (d >> BSHIFT) & (NBKT - 1);
                int p = atomicAdd(&hist[b], 1);
                int g = base_s[b] + p;
                if ((unsigned)g < BCAP)
                    rec[b * BCAP + g] = ((int)(d & 511) << 17) | (s_[k] & 0x1FFFF);
            }
        }
    } else if (blk < CBLK + WPBLK) {
        // ---- W pre-convert + pre-swizzle, hi/lo split ----
        int G = (blk - CBLK) * 1024 + t;
        if (G < 3 * 1536) {
            int l = G / 1536, Gp = G % 1536;
            int mm = Gp >> 9, rem = Gp & 511;
            int kq = rem >> 6, n = rem & 63;
            const float* Wp = Ws + l * 12288 + mm * 4096 + (kq * 8) * 64 + n;
            unsigned short uh[8], ul[8];
#pragma unroll
            for (int j = 0; j < 8; ++j) {
                float w = Wp[j * 64];
                unsigned short hi = f2b(w);
                uh[j] = hi;
                ul[j] = f2b(w - b2f(hi));
            }
            size_t off = (size_t)l * 12288 + (mm << 12) + XSH(n, kq);
            *(short8*)&whi[off] = *(short8*)uh;
            *(short8*)&wlo[off] = *(short8*)ul;
        }
    } else {
        // ---- embedding gather (bf16) + sorted-graph span boundaries ----
        int idx = (blk - CBLK - WPBLK) * 1024 + t;
        if (idx < N_NODES * 32) {
            int n = idx >> 5, cp = idx & 31;
            const float2 e = *(const float2*)(emb + (((size_t)(node_ids[n] + ID_OFFSET)) << 6) + cp * 2);
            unsigned v = (unsigned)f2b(e.x) | ((unsigned)f2b(e.y) << 16);
            ((unsigned*)h)[n * 32 + cp] = v;
            if (cp == 0) {
                int g = gid[n] & (N_GRAPHS - 1);
                if (n == 0 || (gid[n - 1] & (N_GRAPHS - 1)) != g) gs[g] = n;
                if (n == N_NODES - 1 || (gid[n + 1] & (N_GRAPHS - 1)) != g) ge[g] = n + 1;
            }
        }
    }
}

// ---------------- per-bucket CSR fill (pads rows to a multiple of 16) ----------------

__global__ __launch_bounds__(1024) void fill_kernel(const int* __restrict__ rec,
                                                    const int* __restrict__ cursor,
                                                    int* __restrict__ cnt,
                                                    int* __restrict__ srcs) {
    __shared__ int lcnt[512];
    int t = threadIdx.x;
    int b = blockIdx.x;            // 0..NUSED-1
    if (t < 512) lcnt[t] = 0;
    __syncthreads();
    int nb = cursor[b];
    if (nb < 0) nb = 0;
    if (nb > BCAP) nb = BCAP;
    const int* seg = rec + b * BCAP;
    for (int i = t; i < nb; i += 1024) {
        unsigned r = (unsigned)seg[i];
        int dl = (int)((r >> 17) & 511);
        int s = (int)(r & 0x1FFFF);
        int node = (b << BSHIFT) + dl;
        int p = atomicAdd(&lcnt[dl], 1);
        if (p < CAP && node < N_NODES) srcs[(node << 6) + p] = s;
    }
    __syncthreads();
    if (t < 512) {
        int node = (b << BSHIFT) + t;
        if (node < N_NODES) {
            int deg = lcnt[t];
            cnt[node] = deg;
            int degc = deg > CAP ? CAP : deg;
            int degp = (degc + 15) & ~15;
            if (degp < 16) degp = 16;
            // pad with dummy index -> zeroed row; lets gather run unmasked 16-edge chunks
            for (int p = degc; p < degp; ++p) srcs[(node << 6) + p] = DUMMY_ROW;
        }
    }
}

// ---------------- FUSED GIN layer v2: burst-width-engineered ----------------
// R2 failure autopsy: 136-VGPR budget + 64-reg landing zone made the compiler
// chunk-serialize the gather burst (~15 loads in flight/CU -> 560 GB/s). Fix: 4-node
// groups (32-load bursts, the width agg proved at 2.15 TB/s) under a 170-VGPR budget
// (launch_bounds 256,3 = the 3 blocks/CU the 782-block grid gives anyway), no LDS
// weight stage, and ZERO barriers before the final stats reduce so the 12 resident
// waves' gather/MFMA/pool phases interleave freely. MLP rides free under gather
// stalls (proven by R2: fused time == gather-BW time exactly). Deletes the 12.8
// MB/layer x round-trip and one launch per layer.

__global__ __launch_bounds__(256, 3) void fused_kernel(const unsigned short* __restrict__ x,
                                                       unsigned short* __restrict__ xo,
                                                       const int* __restrict__ cnt,
                                                       const int* __restrict__ srcs,
                                                       const float* __restrict__ eps, int l,
                                                       float* __restrict__ stats,
                                                       const float* __restrict__ gamma,
                                                       const float* __restrict__ beta,
                                                       const unsigned short* __restrict__ whi,
                                                       const unsigned short* __restrict__ wlo,
                                                       const float* __restrict__ bs,
                                                       const int* __restrict__ graph_ids,
                                                       float* __restrict__ pooled, int last) {
    __shared__ __align__(16) unsigned short xs[128 * 64];    // 16 KB
    __shared__ int garr[128];
    __shared__ float ssum[256], sqq[256];
    int t = threadIdx.x;
    int nodebase = blockIdx.x * 128;
    int lane = t & 63, w = t >> 6;
    int half = lane >> 5, cl = lane & 31;
    const unsigned* __restrict__ xu = (const unsigned*)x;

    if (lane < 32) {
        int n = nodebase + w * 32 + lane;
        garr[w * 32 + lane] = (n < N_NODES) ? (graph_ids[n] & (N_GRAPHS - 1)) : -1;
    }

    // ---- BN coefficients for layer l-1 (issued early, hide under gather)
    float scale = 1.0f + eps[l];
    float a0f = 1.0f, a1f = 1.0f, b0f = 0.0f, b1f = 0.0f;
    if (l > 0) {
        int lp = l - 1;
        float2 sm = *(const float2*)&stats[lp * 128 + 2 * cl];
        float2 sq = *(const float2*)&stats[lp * 128 + 64 + 2 * cl];
        float2 gm = *(const float2*)&gamma[lp * 64 + 2 * cl];
        float2 bt = *(const float2*)&beta[lp * 64 + 2 * cl];
        float mean0 = sm.x * (1.0f / N_NODES);
        float var0 = sq.x * (1.0f / N_NODES) - mean0 * mean0;
        float r0 = rsqrtf(var0 + BN_EPS);
        a0f = gm.x * r0;
        b0f = bt.x - mean0 * a0f;
        float mean1 = sm.y * (1.0f / N_NODES);
        float var1 = sq.y * (1.0f / N_NODES) - mean1 * mean1;
        float r1 = rsqrtf(var1 + BN_EPS);
        a1f = gm.y * r1;
        b1f = bt.y - mean1 * a1f;
    }

    int wb = __builtin_amdgcn_readfirstlane(nodebase + w * 32);

    // ---- gather-aggregate this wave's 32 rows: 8 groups of 4 nodes (32-load bursts)
    for (int g4 = 0; g4 < 8; ++g4) {
        int nb = wb + g4 * 4;
        int deg[4], degp[4];
        const int* row[4];
#pragma unroll
        for (int n = 0; n < 4; ++n) {
            int d = (nb + n < N_NODES) ? cnt[nb + n] : 0;   // wave-uniform -> s_load
            int dc = d < 0 ? 0 : (d > CAP ? CAP : d);
            deg[n] = dc;
            int dp = (dc + 15) & ~15;
            degp[n] = dp < 16 ? 16 : dp;
            row[n] = srcs + ((size_t)(nb + n) << 6);
        }
        int cmax = degp[0];
        cmax = degp[1] > cmax ? degp[1] : cmax;
        cmax = degp[2] > cmax ? degp[2] : cmax;
        cmax = degp[3] > cmax ? degp[3] : cmax;

        // self rows (issued alongside the gather burst)
        unsigned us[4];
#pragma unroll
        for (int n = 0; n < 4; ++n) us[n] = xu[(size_t)(nb + n) * 32 + cl];

        float A0[4] = {0.f, 0.f, 0.f, 0.f}, A1[4] = {0.f, 0.f, 0.f, 0.f};
        float B0[4] = {0.f, 0.f, 0.f, 0.f}, B1[4] = {0.f, 0.f, 0.f, 0.f};

        // chunk 0: unconditional (rows padded to >=16) -> 32 gathers in flight
        {
            unsigned uv[4][8];
#pragma unroll
            for (int n = 0; n < 4; ++n)
#pragma unroll
                for (int k = 0; k < 8; ++k) {
                    int ia = row[n][2 * k] & 0x1FFFF;
                    int ib = row[n][2 * k + 1] & 0x1FFFF;
                    int idx = half ? ib : ia;
                    uv[n][k] = xu[(size_t)idx * 32 + cl];
                }
#pragma unroll
            for (int n = 0; n < 4; ++n)
#pragma unroll
                for (int k = 0; k < 8; ++k) {
                    float lo = b2f((unsigned short)(uv[n][k] & 0xFFFF));
                    float hi = b2f((unsigned short)(uv[n][k] >> 16));
                    if (k & 1) { B0[n] += lo; B1[n] += hi; }
                    else       { A0[n] += lo; A1[n] += hi; }
                }
        }
        // remainder chunks: wave-uniform scalar branches, issue-all then consume-all
        for (int c = 16; c < cmax; c += 16) {
            unsigned uc[4][8];
#pragma unroll
            for (int n = 0; n < 4; ++n)
                if (c < degp[n])
#pragma unroll
                    for (int k = 0; k < 8; ++k) {
                        int ia = row[n][c + 2 * k] & 0x1FFFF;
                        int ib = row[n][c + 2 * k + 1] & 0x1FFFF;
                        int idx = half ? ib : ia;
                        uc[n][k] = xu[(size_t)idx * 32 + cl];
                    }
#pragma unroll
            for (int n = 0; n < 4; ++n)
                if (c < degp[n])
#pragma unroll
                    for (int k = 0; k < 8; ++k) {
                        float lo = b2f((unsigned short)(uc[n][k] & 0xFFFF));
                        float hi = b2f((unsigned short)(uc[n][k] >> 16));
                        if (k & 1) { B0[n] += lo; B1[n] += hi; }
                        else       { A0[n] += lo; A1[n] += hi; }
                    }
        }

        // reduce + BN affine + write bf16 into swizzled xs (own rows: no barrier)
#pragma unroll
        for (int n = 0; n < 4; ++n) {
            float S0 = A0[n] + B0[n];
            float S1 = A1[n] + B1[n];
            S0 += __shfl_xor(S0, 32);
            S1 += __shfl_xor(S1, 32);
            if (half == 0) {
                float selflo = b2f((unsigned short)(us[n] & 0xFFFF));
                float selfhi = b2f((unsigned short)(us[n] >> 16));
                float db = scale + (float)deg[n];
                float v0 = fmaf(a0f, fmaf(scale, selflo, S0), db * b0f);
                float v1 = fmaf(a1f, fmaf(scale, selfhi, S1), db * b1f);
                int r = w * 32 + g4 * 4 + n;
                int col = 2 * cl;
                *(unsigned*)&xs[XSH(r, col >> 3) + (col & 7)] =
                    (unsigned)f2b(v0) | ((unsigned)f2b(v1) << 16);
            }
        }
    }
    // no barrier: xs rows, garr entries wave-private until the cross-wave stats reduce

    // ---- MFMA MLP (single acc chain, weights straight from global; L2-hot) ----
    int m = lane & 15, q = lane >> 4;
    const float* bb = bs + l * 3 * 64;
    const unsigned short* whil = whi + (size_t)l * 12288;
    const unsigned short* wlol = wlo + (size_t)l * 12288;
    for (int mm = 0; mm < 3; ++mm) {
        // prefetch lo fragments for this mm (global loads go in flight now)
        short8 bl[2][4];
#pragma unroll
        for (int kc = 0; kc < 2; ++kc)
#pragma unroll
            for (int tj = 0; tj < 4; ++tj)
                bl[kc][tj] = *(const short8*)&wlol[(mm << 12) + XSH(tj * 16 + m, kc * 4 + q)];
        // A fragments (LDS, own rows)
        short8 a[2][2];
#pragma unroll
        for (int kc = 0; kc < 2; ++kc)
#pragma unroll
            for (int ti = 0; ti < 2; ++ti)
                a[kc][ti] = *(const short8*)&xs[XSH(w * 32 + ti * 16 + m, kc * 4 + q)];

        floatx4 acc[2][4];
#pragma unroll
        for (int tj = 0; tj < 4; ++tj) {
            float bv = bb[mm * 64 + tj * 16 + m];
#pragma unroll
            for (int ti = 0; ti < 2; ++ti)
                acc[ti][tj] = (floatx4){bv, bv, bv, bv};
        }
        // hi chain
#pragma unroll
        for (int kc = 0; kc < 2; ++kc) {
            short8 bh[4];
#pragma unroll
            for (int tj = 0; tj < 4; ++tj)
                bh[tj] = *(const short8*)&whil[(mm << 12) + XSH(tj * 16 + m, kc * 4 + q)];
#pragma unroll
            for (int ti = 0; ti < 2; ++ti)
#pragma unroll
                for (int tj = 0; tj < 4; ++tj)
                    acc[ti][tj] = __builtin_amdgcn_mfma_f32_16x16x32_bf16(a[kc][ti], bh[tj], acc[ti][tj], 0, 0, 0);
        }
        // lo chain
#pragma unroll
        for (int kc = 0; kc < 2; ++kc)
#pragma unroll
            for (int ti = 0; ti < 2; ++ti)
#pragma unroll
                for (int tj = 0; tj < 4; ++tj)
                    acc[ti][tj] = __builtin_amdgcn_mfma_f32_16x16x32_bf16(a[kc][ti], bl[kc][tj], acc[ti][tj], 0, 0, 0);
        // ReLU + write-back (wave-local rows)
#pragma unroll
        for (int ti = 0; ti < 2; ++ti)
#pragma unroll
            for (int tj = 0; tj < 4; ++tj) {
                int col = tj * 16 + m;
#pragma unroll
                for (int r = 0; r < 4; ++r) {
                    int row = w * 32 + ti * 16 + q * 4 + r;
                    float v = acc[ti][tj][r];
                    xs[XSH(row, col >> 3) + (col & 7)] = f2b(v > 0.f ? v : 0.f);
                }
            }
    }

    if (!last) {
        unsigned* xou = (unsigned*)xo;
#pragma unroll
        for (int it = 0; it < 16; ++it) {
            int row = w * 32 + (lane >> 5) + it * 2;
            int cp = lane & 31;
            int col = cp * 2;
            unsigned val = *(const unsigned*)&xs[XSH(row, col >> 3) + (col & 7)];
            int node = nodebase + row;
            if (node < N_NODES) xou[(size_t)node * 32 + cp] = val;
        }
    }
    {
        int c = lane;
        float s = 0.f, q2 = 0.f, acc2 = 0.f;
        int cur = -1;
        for (int k = 0; k < 32; ++k) {
            int row = w * 32 + k;
            int g = garr[row];
            if (g >= 0) {
                float v = b2f(xs[XSH(row, c >> 3) + (c & 7)]);
                s += v;
                q2 += v * v;
                if (g != cur) {
                    if (cur >= 0) atomicAdd(&pooled[cur * 192 + l * 64 + c], acc2);
                    acc2 = 0.f;
                    cur = g;
                }
                acc2 += v;
            }
        }
        if (cur >= 0) atomicAdd(&pooled[cur * 192 + l * 64 + c], acc2);
        ssum[t] = s;
        sqq[t] = q2;
    }
    __syncthreads();
    if (t < 64) {
        float S = ssum[t] + ssum[t + 64] + ssum[t + 128] + ssum[t + 192];
        float Q = sqq[t] + sqq[t + 64] + sqq[t + 128] + sqq[t + 192];
        atomicAdd(&stats[l * 128 + t], S);
        atomicAdd(&stats[l * 128 + 64 + t], Q);
    }
}

// ---------------- final classifier ----------------

__global__ __launch_bounds__(256) void out_kernel(const float* __restrict__ pooled,
                                                  const float* __restrict__ stats,
                                                  const float* __restrict__ gamma,
                                                  const float* __restrict__ beta,
                                                  const int* __restrict__ gs,
                                                  const int* __restrict__ ge,
                                                  const float* __restrict__ Wo,
                                                  const float* __restrict__ bo,
                                                  float* __restrict__ out) {
    __shared__ float sab[384];
    int t = threadIdx.x;
    if (t < 192) {
        int l2 = t / 64, c = t & 63;
        float mean = stats[l2 * 128 + c] * (1.0f / N_NODES);
        float var = stats[l2 * 128 + 64 + c] * (1.0f / N_NODES) - mean * mean;
        float rstd = rsqrtf(var + BN_EPS);
        float a = gamma[l2 * 64 + c] * rstd;
        sab[l2 * 128 + c] = a;
        sab[l2 * 128 + 64 + c] = beta[l2 * 64 + c] - mean * a;
    }
    __syncthreads();
    int idx = blockIdx.x * blockDim.x + t;
    if (idx < N_GRAPHS * NUM_CLASSES) {
        int g = idx / NUM_CLASSES, k = idx % NUM_CLASSES;
        float cg = (float)(ge[g] - gs[g]);
        float acc = bo[k];
        for (int l2 = 0; l2 < 3; ++l2)
            for (int c = 0; c < 64; ++c) {
                float gf = fmaf(sab[l2 * 128 + c], pooled[g * 192 + l2 * 64 + c],
                                sab[l2 * 128 + 64 + c] * cg);
                acc = fmaf(gf, Wo[(l2 * 64 + c) * NUM_CLASSES + k], acc);
            }
        out[idx] = acc;
    }
}

extern "C" void kernel_launch(void* const* d_in, const int* in_sizes, int n_in,
                              void* d_out, int out_size, void* d_ws, size_t ws_size,
                              hipStream_t stream) {
    const int*   node_ids  = (const int*)d_in[0];
    const int*   edge_src  = (const int*)d_in[1];
    const int*   edge_dst  = (const int*)d_in[2];
    const int*   graph_ids = (const int*)d_in[3];
    const float* emb       = (const float*)d_in[4];
    const float* Ws        = (const float*)d_in[5];
    const float* bs        = (const float*)d_in[6];
    const float* gamma     = (const float*)d_in[7];
    const float* beta      = (const float*)d_in[8];
    const float* eps       = (const float*)d_in[9];
    const float* W_out     = (const float*)d_in[10];
    const float* b_out     = (const float*)d_in[11];
    float* out = (float*)d_out;

    // workspace
    unsigned short* h    = (unsigned short*)d_ws;         // 6,400,000 sh (+8192 slack)
    unsigned short* xin  = h + 6400000 + 8192;            // 6,400,000 sh (+8192 slack)
    unsigned short* whi  = xin + 6400000 + 8192;          // 36,864 sh
    unsigned short* wlo  = whi + 36864;                   // 36,864 sh
    int*   srcs   = (int*)(wlo + 36864);                  // 6,400,000 i (padded CSR)
    int*   rec    = srcs + 6400000;                       // NUSED*BCAP i
    float* pooled = (float*)(rec + NUSED * BCAP);         // 98,304 f
    float* stats  = pooled + 98304;                       // 384 f
    int*   cnt    = (int*)(stats + 384);                  // 100,000 i
    int*   gs     = cnt + 100000;                         // 512 i
    int*   ge     = gs + 512;                             // 512 i
    int*   cursor = ge + 512;                             // 256 i (bucket totals)

    hipMemsetAsync(pooled, 0,
                   (size_t)(98304 + 384 + 100000 + 512 + 512 + 256) * 4, stream);

    prep_kernel<<<CBLK + WPBLK + EMBBLK, 1024, 0, stream>>>(
        edge_src, edge_dst, cursor, rec, Ws, whi, wlo,
        node_ids, graph_ids, emb, h, xin, gs, ge);
    fill_kernel<<<NUSED, 1024, 0, stream>>>(rec, cursor, cnt, srcs);

    const int FUSE_BLK = (N_NODES + 127) / 128;   // 782
    for (int l = 0; l < 3; ++l) {
        const unsigned short* X = (l % 2 == 0) ? h : xin;   // gather source
        unsigned short* A = (l % 2 == 0) ? xin : h;         // this-layer output
        fused_kernel<<<FUSE_BLK, 256, 0, stream>>>(
            X, A, cnt, srcs, eps, l, stats, gamma, beta,
            whi, wlo, bs, graph_ids, pooled, l == 2);
    }

    out_kernel<<<(N_GRAPHS * NUM_CLASSES + 255) / 256, 256, 0, stream>>>(
        pooled, stats, gamma, beta, gs, ge, W_out, b_out, out);
}